// Round 13
// baseline (40.254 us; speedup 1.0000x reference)
//
#include <hip/hip_runtime.h>

#define NF       10000
#define NF_PAD   10240
#define PATCH    16
#define ENC      128
#define BB       8
#define HH       64
#define WW       32
#define NPOS     (BB*HH*WW)   // 16384
#define QPW      16           // queries per wave (4 waves x 16 = 64 = block group)

// f32 sum of 16, shuffle-halving tree order (CONFIRMED ref order, R7-R12 PASS).
__device__ __forceinline__ float tree_sum16(const float* a) {
    float b0 = a[0] + a[8],  b1 = a[1] + a[9],  b2 = a[2] + a[10], b3 = a[3] + a[11];
    float b4 = a[4] + a[12], b5 = a[5] + a[13], b6 = a[6] + a[14], b7 = a[7] + a[15];
    float c0 = b0 + b4, c1 = b1 + b5, c2 = b2 + b6, c3 = b3 + b7;
    float d0 = c0 + c2, d1 = c1 + c3;
    return d0 + d1;
}

// ---------------------------------------------------------------------------
// ONE fused kernel. Block = one (b,w) group = 64 queries. 256 blocks = 1/CU.
//  A: block-local x_sum (VERBATIM R11 — bit-exact, verified).
//  B: fs[0..10239] -> LDS by direct store (no atomics; +inf pad).
//  C: brute argmin, 16 queries per wave amortized over one LDS scan.
//     Two-pass exact semantics: pass1 tracks (min, last-strict-improvement
//     chunk); last strict improvement == first chunk attaining the final min,
//     so rescanning that 4-cand chunk (reverse overwrite) + cross-lane
//     min(idx) == exact first-occurrence argmin (R8-verified pattern).
//  D: gather emb rows (VERBATIM R11).
// LDS ~= 46 KB. ONE dispatch (the 4-round fit says dispatch overhead ~5 us).
// ---------------------------------------------------------------------------
__global__ __launch_bounds__(256, 1) void fused_kernel(
        const float* __restrict__ x, const float* __restrict__ filters,
        const float* __restrict__ emb, float* __restrict__ out) {
    __shared__ float fsld[NF_PAD];       // 40 KB
    __shared__ float lds[64][17];
    __shared__ float smn[16], sinv[16];
    __shared__ float sxsum[64];
    __shared__ int   sidx[64];

    int tid  = threadIdx.x;
    int lane = tid & 63, wv = tid >> 6;
    int g = blockIdx.x;                  // (b,w) group 0..255
    int b = g >> 5, w = g & 31;

    // ---- A1: load own x row (h = tid < 64), stage to LDS ------------------
    float vv[16];
    if (tid < 64) {
        const float4* xp = reinterpret_cast<const float4*>(
            x + (size_t)(((b * HH + tid) * WW + w) * PATCH));
        float4 v0 = xp[0], v1 = xp[1], v2 = xp[2], v3 = xp[3];
        vv[0]=v0.x; vv[1]=v0.y; vv[2]=v0.z; vv[3]=v0.w;
        vv[4]=v1.x; vv[5]=v1.y; vv[6]=v1.z; vv[7]=v1.w;
        vv[8]=v2.x; vv[9]=v2.y; vv[10]=v2.z; vv[11]=v2.w;
        vv[12]=v3.x; vv[13]=v3.y; vv[14]=v3.z; vv[15]=v3.w;
        #pragma unroll
        for (int j = 0; j < 16; ++j) lds[tid][j] = vv[j];
    }
    __syncthreads();
    // ---- A2: min/max over h (bit-exact R7 sequential order) ---------------
    if (tid < 16) {
        float mn = lds[0][tid], mx = mn;
        for (int i = 1; i < 64; ++i) {
            float t = lds[i][tid];
            mn = fminf(mn, t);
            mx = fmaxf(mx, t);
        }
        smn[tid] = mn;
        float rg = (mx - mn) + 1e-8f;    // f32, reference order
        sinv[tid] = 1.0f / rg;           // hoisted reciprocal (R7-confirmed)
    }
    __syncthreads();
    // ---- A3: x_sum --------------------------------------------------------
    if (tid < 64) {
        float xs[16];
        #pragma unroll
        for (int j = 0; j < 16; ++j) xs[j] = (vv[j] - smn[j]) * sinv[j];
        sxsum[tid] = tree_sum16(xs);
    }

    // ---- B: fs -> LDS (direct store, +inf pad; bit-exact tree order) ------
    for (int i = 0; i < NF_PAD / 256; ++i) {     // 40 iters
        int n = i * 256 + tid;
        float val = __builtin_inff();
        if (n < NF) {
            const float4* fp = reinterpret_cast<const float4*>(filters + n * PATCH);
            float4 f0 = fp[0], f1 = fp[1], f2 = fp[2], f3 = fp[3];
            float a[16] = {f0.x, f0.y, f0.z, f0.w, f1.x, f1.y, f1.z, f1.w,
                           f2.x, f2.y, f2.z, f2.w, f3.x, f3.y, f3.z, f3.w};
            val = tree_sum16(a);
        }
        fsld[n] = val;
    }
    __syncthreads();

    // ---- C: brute argmin, 16 queries/wave ---------------------------------
    float s[QPW], m[QPW];
    int lastit[QPW];
    #pragma unroll
    for (int j = 0; j < QPW; ++j) {
        s[j] = sxsum[wv * QPW + j];
        m[j] = __builtin_inff();
        lastit[j] = 0;
    }
    const float4* f4p = reinterpret_cast<const float4*>(fsld);
    #pragma unroll 4
    for (int it = 0; it < 40; ++it) {
        float4 c = f4p[it * 64 + lane];          // cands it*256 + lane*4 + k
        #pragma unroll
        for (int j = 0; j < QPW; ++j) {
            float d0 = fabsf(c.x - s[j]);        // exact ref arithmetic
            float d1 = fabsf(c.y - s[j]);
            float d2 = fabsf(c.z - s[j]);
            float d3 = fabsf(c.w - s[j]);
            float d4 = fminf(fminf(d0, d1), fminf(d2, d3));
            if (d4 < m[j]) { m[j] = d4; lastit[j] = it; }   // strict improve
        }
    }
    #pragma unroll
    for (int j = 0; j < QPW; ++j) {
        float M = m[j];
        #pragma unroll
        for (int d = 1; d < 64; d <<= 1) M = fminf(M, __shfl_xor(M, d, 64));
        int li = 0x7fffffff;
        if (m[j] == M) {
            // first local occurrence lives in chunk lastit[j] (see header)
            float4 c = f4p[lastit[j] * 64 + lane];
            int base = lastit[j] * 256 + lane * 4;
            if (fabsf(c.w - s[j]) == M) li = base + 3;   // reverse overwrite
            if (fabsf(c.z - s[j]) == M) li = base + 2;   //  -> keeps first
            if (fabsf(c.y - s[j]) == M) li = base + 1;
            if (fabsf(c.x - s[j]) == M) li = base + 0;
        }
        #pragma unroll
        for (int d = 1; d < 64; d <<= 1) li = min(li, __shfl_xor(li, d, 64));
        if (lane == 0) sidx[wv * QPW + j] = li;
    }
    __syncthreads();

    // ---- D: gather, wave-per-row, float2 lanes (VERBATIM R11) -------------
    for (int i = wv; i < 64; i += 4) {
        int bi  = sidx[i];
        int pos = (b * HH + i) * WW + w;
        const float2* er = reinterpret_cast<const float2*>(emb + (size_t)bi * ENC);
        float2*       op = reinterpret_cast<float2*>(out + (size_t)pos * ENC);
        op[lane] = er[lane];
    }
}

// ---------------------------------------------------------------------------
extern "C" void kernel_launch(void* const* d_in, const int* in_sizes, int n_in,
                              void* d_out, int out_size, void* d_ws, size_t ws_size,
                              hipStream_t stream) {
    const float* x       = (const float*)d_in[0];  // (8,64,32,16)
    const float* filters = (const float*)d_in[1];  // (10000,16)
    const float* emb     = (const float*)d_in[2];  // (10000,128)
    float* out = (float*)d_out;                    // (8,64,32,128)

    fused_kernel<<<256, 256, 0, stream>>>(x, filters, emb, out);
}